// Round 11
// baseline (173.402 us; speedup 1.0000x reference)
//
#include <hip/hip_runtime.h>
#include <math.h>

#define D_MODEL 512
#define NHEAD   8
#define DK      64
#define BATCH   4
#define SEQ     2048
#define MTOT    (BATCH*SEQ)

typedef _Float16 half8   __attribute__((ext_vector_type(8)));
typedef _Float16 half4_t __attribute__((ext_vector_type(4)));
typedef __fp16   fp16x2  __attribute__((ext_vector_type(2)));  // cvt_pkrtz return type
typedef float    f32x4   __attribute__((ext_vector_type(4)));

#define MFMA32(a,b,c) __builtin_amdgcn_mfma_f32_16x16x32_f16((a),(b),(c),0,0,0)

// wave scale: dk^-0.5 * log2(e)  (log2e folded so attn uses raw v_exp_f32)
#define WSCALE 0.18033688011117130f

// ---------------------------------------------------------------------------
// Kernel 1: fused QKV projection, fp16 MFMA, FP32 INPUTS CONVERTED INLINE.
//   One block computes Q,K,V for one (h, 128-row m-tile); X tile read once
//   per h.  blockIdx.x == h == XCD (round-robin) -> W stays L2-resident.
//   Q out: (B,H,L,64) fp16 raw.
//   K out: (B,H,L,64) fp16, PRE-MULTIPLIED by WSCALE*cos(2pi f h pos + ph)
//          (wave table computed inline - no cvt kernel, no wtab).
//   V out: transposed (B,H,64,L') fp16, pos swizzled per 32-key group so a
//          b128 read at [d][g*32+quad*8] is a K=32 PV B-fragment.
// grid: (8, 64), block 256
// ---------------------------------------------------------------------------
__global__ __launch_bounds__(256) void qkv_mfma_kernel(
    const float* __restrict__ x,
    const float* __restrict__ Wq, const float* __restrict__ Wk,
    const float* __restrict__ Wv,
    const float* __restrict__ wf, const float* __restrict__ wp,
    _Float16* __restrict__ Qh, _Float16* __restrict__ Kh,
    _Float16* __restrict__ Vth)
{
    __shared__ _Float16 As[128][72];   // [m][k], pad 8          18.4 KB
    __shared__ _Float16 Bs[192][72];   // [which*64 + n][k]      27.6 KB

    const int t  = threadIdx.x;
    const int h  = blockIdx.x;
    const int m0 = blockIdx.y * 128;

    const int w = t >> 6, lane = t & 63, ln = lane & 15, quad = lane >> 4;
    const int ar = t >> 1, ac = (t & 1) * 32;
    const int br = t >> 2, bc = (t & 3) * 16;

    const float* agf  = x  + (size_t)(m0 + ar) * 512 + ac;
    const float* bgf0 = Wq + (size_t)(h * 64 + br) * 512 + bc;
    const float* bgf1 = Wk + (size_t)(h * 64 + br) * 512 + bc;
    const float* bgf2 = Wv + (size_t)(h * 64 + br) * 512 + bc;

    const f32x4 kZero = {0.f, 0.f, 0.f, 0.f};
    f32x4 acc[3][2][4];
    #pragma unroll
    for (int c = 0; c < 3; ++c)
        #pragma unroll
        for (int i = 0; i < 2; ++i)
            #pragma unroll
            for (int j = 0; j < 4; ++j) acc[c][i][j] = kZero;

    for (int k0 = 0; k0 < 512; k0 += 64) {
        // load fp32, convert RTN immediately (same rounding as old cvt kernel)
        half8 av[4], bv[6];
        #pragma unroll
        for (int i = 0; i < 4; ++i) {
            float4 f0 = *(const float4*)(agf + k0 + i * 8);
            float4 f1 = *(const float4*)(agf + k0 + i * 8 + 4);
            half8 hv;
            hv[0] = (_Float16)f0.x; hv[1] = (_Float16)f0.y;
            hv[2] = (_Float16)f0.z; hv[3] = (_Float16)f0.w;
            hv[4] = (_Float16)f1.x; hv[5] = (_Float16)f1.y;
            hv[6] = (_Float16)f1.z; hv[7] = (_Float16)f1.w;
            av[i] = hv;
        }
        #pragma unroll
        for (int c = 0; c < 3; ++c) {
            const float* bp = (c == 0) ? bgf0 : (c == 1) ? bgf1 : bgf2;
            #pragma unroll
            for (int i = 0; i < 2; ++i) {
                float4 f0 = *(const float4*)(bp + k0 + i * 8);
                float4 f1 = *(const float4*)(bp + k0 + i * 8 + 4);
                half8 hv;
                hv[0] = (_Float16)f0.x; hv[1] = (_Float16)f0.y;
                hv[2] = (_Float16)f0.z; hv[3] = (_Float16)f0.w;
                hv[4] = (_Float16)f1.x; hv[5] = (_Float16)f1.y;
                hv[6] = (_Float16)f1.z; hv[7] = (_Float16)f1.w;
                bv[c * 2 + i] = hv;
            }
        }
        __syncthreads();
        #pragma unroll
        for (int i = 0; i < 4; ++i) *(half8*)&As[ar][ac + i * 8] = av[i];
        #pragma unroll
        for (int c = 0; c < 3; ++c) {
            *(half8*)&Bs[c * 64 + br][bc]     = bv[2 * c];
            *(half8*)&Bs[c * 64 + br][bc + 8] = bv[2 * c + 1];
        }
        __syncthreads();

        #pragma unroll
        for (int ks = 0; ks < 2; ++ks) {
            half8 af[2];
            #pragma unroll
            for (int mt = 0; mt < 2; ++mt)
                af[mt] = *(const half8*)&As[w * 32 + mt * 16 + ln][ks * 32 + quad * 8];
            #pragma unroll
            for (int c = 0; c < 3; ++c) {
                half8 bf[4];
                #pragma unroll
                for (int nt = 0; nt < 4; ++nt)
                    bf[nt] = *(const half8*)&Bs[c * 64 + nt * 16 + ln][ks * 32 + quad * 8];
                #pragma unroll
                for (int mt = 0; mt < 2; ++mt)
                    #pragma unroll
                    for (int nt = 0; nt < 4; ++nt)
                        acc[c][mt][nt] = MFMA32(af[mt], bf[nt], acc[c][mt][nt]);
            }
        }
    }

    const int b  = m0 >> 11;
    const int l0 = m0 & 2047;
    const float twopif = 6.28318530717958647692f * wf[h];
    const float ph     = wp[h];

    #pragma unroll
    for (int which = 0; which < 2; ++which) {
        _Float16* dst = (which == 0 ? Qh : Kh) + (size_t)(b * NHEAD + h) * SEQ * DK;
        __syncthreads();
        _Float16* Ql = &As[0][0];
        #pragma unroll
        for (int mt = 0; mt < 2; ++mt)
            #pragma unroll
            for (int r = 0; r < 4; ++r) {
                const int lr = w * 32 + mt * 16 + quad * 4 + r;
                float wv = 1.0f;
                if (which == 1)
                    wv = WSCALE * cosf(fmaf(twopif, (float)(l0 + lr), ph));
                #pragma unroll
                for (int nt = 0; nt < 4; ++nt)
                    Ql[lr * 72 + nt * 16 + ln] = (_Float16)(acc[which][mt][nt][r] * wv);
            }
        __syncthreads();
        #pragma unroll
        for (int rr = 0; rr < 4; ++rr) {
            const int row = rr * 32 + (t >> 3);
            half8 v = *(const half8*)&Ql[row * 72 + (t & 7) * 8];
            *(half8*)(dst + (size_t)(l0 + row) * DK + (t & 7) * 8) = v;
        }
    }

    __syncthreads();
    _Float16* Vl = &As[0][0];
    #pragma unroll
    for (int nt = 0; nt < 4; ++nt) {
        half8 hv;
        #pragma unroll
        for (int mt = 0; mt < 2; ++mt)
            #pragma unroll
            for (int r = 0; r < 4; ++r)
                hv[mt * 4 + r] = (_Float16)acc[2][mt][nt][r];
        const int d = nt * 16 + ln;
        *(half8*)&Vl[d * 136 + w * 32 + quad * 8] = hv;
    }
    __syncthreads();
    _Float16* dst = Vth + (size_t)(b * NHEAD + h) * DK * SEQ;
    #pragma unroll
    for (int rr = 0; rr < 4; ++rr) {
        const int d = rr * 16 + (t >> 4);
        half8 v = *(const half8*)&Vl[d * 136 + (t & 15) * 8];
        *(half8*)(dst + (size_t)d * SEQ + l0 + (t & 15) * 8) = v;
    }
}

// ---------------------------------------------------------------------------
// Kernel 2: flash attention — EXACT round-9 kernel (best measured: 45.9 us).
//   512 threads / 8 waves; waves 0-3 keys 0..1023, waves 4-7 keys 1024..2047,
//   each half double-buffered; max-free softmax (exact split); two barriers
//   per tile; register prefetch; XCD swizzle.
// grid: 512 linear, block 512
// ---------------------------------------------------------------------------
__global__ __launch_bounds__(512, 4) void attn_mfma_kernel(
    const _Float16* __restrict__ Qh, const _Float16* __restrict__ Kwh,
    const _Float16* __restrict__ Vth, _Float16* __restrict__ AOh)
{
    __shared__ _Float16 SM[2][4][64][72];   // 73.7 KB

    const int bx = blockIdx.x;           // 0..511
    const int g8 = bx & 7;               // XCD (dispatch round-robin)
    const int s  = bx >> 3;              // 0..63
    const int bh = g8 * 4 + (s >> 4);    // XCD g owns bh 4g..4g+3
    const int q0 = (s & 15) * 128;
    const int b = bh >> 3, h = bh & 7;

    const int t = threadIdx.x;           // 0..511
    const int w = t >> 6;                // 0..7
    const int wg = w & 3;                // q-row group
    const int half = w >> 2;             // key half
    const int lane = t & 63, ln = lane & 15, quad = lane >> 4;

    const _Float16* Qg = Qh + ((size_t)bh * SEQ + q0) * DK;
    const _Float16* Kg = Kwh + (size_t)bh * SEQ * DK;
    const _Float16* Vg = Vth + (size_t)bh * DK * SEQ;
    const int kbase = half * 1024;

    const int tl = t & 255;
    const int sr = tl >> 2, sc = (tl & 3) * 16;
    const int qr = t >> 2, qc = (t & 3) * 16;

    {
        const _Float16* qp = Qg + (size_t)qr * DK + qc;
        half8 qv0 = *(const half8*)(qp);
        half8 qv1 = *(const half8*)(qp + 8);
        const _Float16* kp = Kg + (size_t)(kbase + sr) * DK + sc;
        const _Float16* vp = Vg + (size_t)sr * SEQ + kbase + sc;
        half8 kv0 = *(const half8*)(kp);
        half8 kv1 = *(const half8*)(kp + 8);
        half8 vv0 = *(const half8*)(vp);
        half8 vv1 = *(const half8*)(vp + 8);
        _Float16* qd = &SM[1][2 + (qr >> 6)][qr & 63][qc];
        *(half8*)(qd)     = qv0;
        *(half8*)(qd + 8) = qv1;
        *(half8*)&SM[half][0][sr][sc]     = kv0;
        *(half8*)&SM[half][0][sr][sc + 8] = kv1;
        *(half8*)&SM[half][1][sr][sc]     = vv0;
        *(half8*)&SM[half][1][sr][sc + 8] = vv1;
    }
    __syncthreads();

    half8 qf[2][2];
    #pragma unroll
    for (int u = 0; u < 2; ++u) {
        const int row = wg * 32 + u * 16 + ln;
        const _Float16* qsrc = &SM[1][2 + (row >> 6)][row & 63][0];
        qf[u][0] = *(const half8*)(qsrc + quad * 8);
        qf[u][1] = *(const half8*)(qsrc + 32 + quad * 8);
    }
    // first write to SM[1][2..3] happens only after kt=0's in-loop barrier

    const f32x4 kZero = {0.f, 0.f, 0.f, 0.f};
    f32x4 o[2][4];
    #pragma unroll
    for (int u = 0; u < 2; ++u)
        #pragma unroll
        for (int nt = 0; nt < 4; ++nt) o[u][nt] = kZero;
    float l_acc[2] = {0.f, 0.f};

    for (int kt = 0; kt < 16; ++kt) {
        const int cur = kt & 1;

        half8 pk0, pk1, pv0, pv1;
        const bool more = (kt + 1 < 16);
        if (more) {
            const _Float16* kp = Kg + (size_t)(kbase + (kt + 1) * 64 + sr) * DK + sc;
            const _Float16* vp = Vg + (size_t)sr * SEQ + kbase + (kt + 1) * 64 + sc;
            pk0 = *(const half8*)(kp);
            pk1 = *(const half8*)(kp + 8);
            pv0 = *(const half8*)(vp);
            pv1 = *(const half8*)(vp + 8);
        }

        const _Float16 (*Ks)[72] = SM[half][2 * cur];
        const _Float16 (*Vs)[72] = SM[half][2 * cur + 1];

        #pragma unroll
        for (int g = 0; g < 2; ++g) {
            half8 ka0 = *(const half8*)&Ks[(2 * g + 0) * 16 + ln][quad * 8];
            half8 ka1 = *(const half8*)&Ks[(2 * g + 0) * 16 + ln][32 + quad * 8];
            half8 kb0 = *(const half8*)&Ks[(2 * g + 1) * 16 + ln][quad * 8];
            half8 kb1 = *(const half8*)&Ks[(2 * g + 1) * 16 + ln][32 + quad * 8];
            half8 vf[4];
            #pragma unroll
            for (int nt = 0; nt < 4; ++nt)
                vf[nt] = *(const half8*)&Vs[nt * 16 + ln][g * 32 + quad * 8];

            #pragma unroll
            for (int u = 0; u < 2; ++u) {
                f32x4 s0 = MFMA32(ka0, qf[u][0], kZero);
                f32x4 s1 = MFMA32(kb0, qf[u][0], kZero);
                s0 = MFMA32(ka1, qf[u][1], s0);
                s1 = MFMA32(kb1, qf[u][1], s1);

                const float e00 = __builtin_amdgcn_exp2f(s0[0]);
                const float e01 = __builtin_amdgcn_exp2f(s0[1]);
                const float e02 = __builtin_amdgcn_exp2f(s0[2]);
                const float e03 = __builtin_amdgcn_exp2f(s0[3]);
                const float e10 = __builtin_amdgcn_exp2f(s1[0]);
                const float e11 = __builtin_amdgcn_exp2f(s1[1]);
                const float e12 = __builtin_amdgcn_exp2f(s1[2]);
                const float e13 = __builtin_amdgcn_exp2f(s1[3]);
                union { half8 v; fp16x2 h2[4]; } pu;
                pu.h2[0] = __builtin_amdgcn_cvt_pkrtz(e00, e01);
                pu.h2[1] = __builtin_amdgcn_cvt_pkrtz(e02, e03);
                pu.h2[2] = __builtin_amdgcn_cvt_pkrtz(e10, e11);
                pu.h2[3] = __builtin_amdgcn_cvt_pkrtz(e12, e13);
                l_acc[u] += ((e00 + e01) + (e02 + e03)) + ((e10 + e11) + (e12 + e13));

                #pragma unroll
                for (int nt = 0; nt < 4; ++nt)
                    o[u][nt] = MFMA32(pu.v, vf[nt], o[u][nt]);
            }
        }

        __syncthreads();
        if (more) {
            _Float16* kd = &SM[half][2 * (cur ^ 1)][sr][sc];
            _Float16* vd = &SM[half][2 * (cur ^ 1) + 1][sr][sc];
            *(half8*)(kd)     = pk0;
            *(half8*)(kd + 8) = pk1;
            *(half8*)(vd)     = pv0;
            *(half8*)(vd + 8) = pv1;
        }
        __syncthreads();
    }

    float* OP = (float*)&SM[0][0][0][0];      // 34 slots x 257 floats
    const int idx = wg * 64 + lane;
    if (half == 1) {
        #pragma unroll
        for (int u = 0; u < 2; ++u)
            #pragma unroll
            for (int nt = 0; nt < 4; ++nt)
                #pragma unroll
                for (int r = 0; r < 4; ++r)
                    OP[((u * 4 + nt) * 4 + r) * 257 + idx] = o[u][nt][r];
        OP[32 * 257 + idx] = l_acc[0];
        OP[33 * 257 + idx] = l_acc[1];
    }
    __syncthreads();
    if (half == 0) {
        #pragma unroll
        for (int u = 0; u < 2; ++u)
            #pragma unroll
            for (int nt = 0; nt < 4; ++nt)
                #pragma unroll
                for (int r = 0; r < 4; ++r)
                    o[u][nt][r] += OP[((u * 4 + nt) * 4 + r) * 257 + idx];
        l_acc[0] += OP[32 * 257 + idx];
        l_acc[1] += OP[33 * 257 + idx];

        #pragma unroll
        for (int u = 0; u < 2; ++u) {
            l_acc[u] += __shfl_xor(l_acc[u], 16);
            l_acc[u] += __shfl_xor(l_acc[u], 32);
        }

        #pragma unroll
        for (int u = 0; u < 2; ++u)
            #pragma unroll
            for (int r = 0; r < 4; ++r) {
                const float lr  = __shfl(l_acc[u], quad * 4 + r, 16);
                const float inv = 1.0f / lr;
                const int lq = q0 + wg * 32 + u * 16 + quad * 4 + r;
                const size_t base = ((size_t)b * SEQ + lq) * D_MODEL + h * DK;
                #pragma unroll
                for (int nt = 0; nt < 4; ++nt)
                    AOh[base + nt * 16 + ln] = (_Float16)(o[u][nt][r] * inv);
            }
    }
}

// ---------------------------------------------------------------------------
// Kernel 3: output projection, fp16 MFMA.  out = AOh @ Wo^T (fp32 out),
//   Wo read fp32 and converted inline (RTN).  Two-pass LDS repack epilogue.
// grid: (8, 64), block 256
// ---------------------------------------------------------------------------
__global__ __launch_bounds__(256) void out_mfma_kernel(
    const _Float16* __restrict__ AOh, const float* __restrict__ Wo,
    float* __restrict__ out)
{
    __shared__ _Float16 As[128][72];
    __shared__ _Float16 Bs[64][72];

    const int t  = threadIdx.x;
    const int n0 = blockIdx.x * 64;
    const int m0 = blockIdx.y * 128;

    const int w = t >> 6, lane = t & 63, ln = lane & 15, quad = lane >> 4;
    const int ar = t >> 1, ac = (t & 1) * 32;
    const int br = t >> 2, bc = (t & 3) * 16;

    const _Float16* ag  = AOh + (size_t)(m0 + ar) * 512 + ac;
    const float*    bgf = Wo  + (size_t)(n0 + br) * 512 + bc;

    const f32x4 kZero = {0.f, 0.f, 0.f, 0.f};
    f32x4 acc[2][4];
    #pragma unroll
    for (int i = 0; i < 2; ++i)
        #pragma unroll
        for (int j = 0; j < 4; ++j) acc[i][j] = kZero;

    for (int k0 = 0; k0 < 512; k0 += 64) {
        half8 av[4], bv[2];
        #pragma unroll
        for (int i = 0; i < 4; ++i) av[i] = *(const half8*)(ag + k0 + i * 8);
        #pragma unroll
        for (int i = 0; i < 2; ++i) {
            float4 f0 = *(const float4*)(bgf + k0 + i * 8);
            float4 f1 = *(const float4*)(bgf + k0 + i * 8 + 4);
            half8 hv;
            hv[0] = (_Float16)f0.x; hv[1] = (_Float16)f0.y;
            hv[2] = (_Float16)f0.z; hv[3] = (_Float16)f0.w;
            hv[4] = (_Float16)f1.x; hv[5] = (_Float16)f1.y;
            hv[6] = (_Float16)f1.z; hv[7] = (_Float16)f1.w;
            bv[i] = hv;
        }
        __syncthreads();
        #pragma unroll
        for (int i = 0; i < 4; ++i) *(half8*)&As[ar][ac + i * 8] = av[i];
        #pragma unroll
        for (int i = 0; i < 2; ++i) *(half8*)&Bs[br][bc + i * 8] = bv[i];
        __syncthreads();

        #pragma unroll
        for (int ks = 0; ks < 2; ++ks) {
            half8 af[2], bf[4];
            #pragma unroll
            for (int mt = 0; mt < 2; ++mt)
                af[mt] = *(const half8*)&As[w * 32 + mt * 16 + ln][ks * 32 + quad * 8];
            #pragma unroll
            for (int nt = 0; nt < 4; ++nt)
                bf[nt] = *(const half8*)&Bs[nt * 16 + ln][ks * 32 + quad * 8];
            #pragma unroll
            for (int mt = 0; mt < 2; ++mt)
                #pragma unroll
                for (int nt = 0; nt < 4; ++nt)
                    acc[mt][nt] = MFMA32(af[mt], bf[nt], acc[mt][nt]);
        }
    }

    float* Os = (float*)&As[0][0];     // [64][66] floats
    #pragma unroll
    for (int pass = 0; pass < 2; ++pass) {
        __syncthreads();
        if ((w >> 1) == pass) {
            const int rbase = (w & 1) * 32;
            #pragma unroll
            for (int mt = 0; mt < 2; ++mt)
                #pragma unroll
                for (int r = 0; r < 4; ++r) {
                    const int row = rbase + mt * 16 + quad * 4 + r;
                    #pragma unroll
                    for (int nt = 0; nt < 4; ++nt)
                        Os[row * 66 + nt * 16 + ln] = acc[mt][nt][r];
                }
        }
        __syncthreads();
        #pragma unroll
        for (int rr = 0; rr < 4; ++rr) {
            const int row = rr * 16 + (t >> 4);
            float4 v = *(const float4*)&Os[row * 66 + (t & 15) * 4];
            *(float4*)(out + (size_t)(m0 + pass * 64 + row) * 512 + n0 + (t & 15) * 4) = v;
        }
    }
}

// ---------------------------------------------------------------------------
extern "C" void kernel_launch(void* const* d_in, const int* in_sizes, int n_in,
                              void* d_out, int out_size, void* d_ws, size_t ws_size,
                              hipStream_t stream)
{
    (void)in_sizes; (void)n_in; (void)out_size; (void)ws_size;
    const float* x  = (const float*)d_in[0];
    const float* Wq = (const float*)d_in[1];
    const float* Wk = (const float*)d_in[2];
    const float* Wv = (const float*)d_in[3];
    const float* Wo = (const float*)d_in[4];
    const float* wf = (const float*)d_in[5];
    const float* wp = (const float*)d_in[6];
    float* out = (float*)d_out;

    const size_t NX = (size_t)MTOT * D_MODEL;        // 4,194,304
    _Float16* Qh  = (_Float16*)d_ws;
    _Float16* Kh  = Qh + NX;                          // pre-scaled K'
    _Float16* Vth = Kh + NX;                          // transposed+swizzled V
    _Float16* AOh = Vth + NX;

    dim3 g1(8, 64);
    qkv_mfma_kernel<<<g1, 256, 0, stream>>>(x, Wq, Wk, Wv, wf, wp, Qh, Kh, Vth);

    attn_mfma_kernel<<<512, 512, 0, stream>>>(Qh, Kh, Vth, AOh);

    dim3 g3(8, 64);
    out_mfma_kernel<<<g3, 256, 0, stream>>>(AOh, Wo, out);
}

// Round 12
// 165.242 us; speedup vs baseline: 1.0494x; 1.0494x over previous
//
#include <hip/hip_runtime.h>
#include <math.h>

#define D_MODEL 512
#define NHEAD   8
#define DK      64
#define BATCH   4
#define SEQ     2048
#define MTOT    (BATCH*SEQ)

typedef _Float16 half8   __attribute__((ext_vector_type(8)));
typedef _Float16 half4_t __attribute__((ext_vector_type(4)));
typedef __fp16   fp16x2  __attribute__((ext_vector_type(2)));  // cvt_pkrtz return type
typedef float    f32x4   __attribute__((ext_vector_type(4)));

#define MFMA32(a,b,c) __builtin_amdgcn_mfma_f32_16x16x32_f16((a),(b),(c),0,0,0)

// wave scale: dk^-0.5 * log2(e)  (log2e folded so attn uses raw v_exp_f32)
#define WSCALE 0.18033688011117130f

// ---------------------------------------------------------------------------
// Kernel 1: fused QKV projection, fp16 MFMA, fp32 inputs converted inline.
//   GRID ORDER FIX: blockIdx.x = m-tile (fast) -> XCD = m%8 -> all 8 h-blocks
//   for one X tile share one XCD's L2 (X HBM traffic 134 -> ~17 MB).
//   Q out: (B,H,L,64) fp16 raw.
//   K out: (B,H,L,64) fp16, PRE-MULTIPLIED by WSCALE*cos(2pi f_h pos + ph).
//   V out: transposed (B,H,64,L') fp16, pos swizzled per 32-key group so a
//          b128 read at [d][g*32+quad*8] is a K=32 PV B-fragment.
// grid: (64, 8), block 256
// ---------------------------------------------------------------------------
__global__ __launch_bounds__(256) void qkv_mfma_kernel(
    const float* __restrict__ x,
    const float* __restrict__ Wq, const float* __restrict__ Wk,
    const float* __restrict__ Wv,
    const float* __restrict__ wf, const float* __restrict__ wp,
    _Float16* __restrict__ Qh, _Float16* __restrict__ Kh,
    _Float16* __restrict__ Vth)
{
    __shared__ _Float16 As[128][72];   // [m][k], pad 8          18.4 KB
    __shared__ _Float16 Bs[192][72];   // [which*64 + n][k]      27.6 KB

    const int t  = threadIdx.x;
    const int m0 = blockIdx.x * 128;   // FAST dim -> XCD = blockIdx.x % 8
    const int h  = blockIdx.y;

    const int w = t >> 6, lane = t & 63, ln = lane & 15, quad = lane >> 4;
    const int ar = t >> 1, ac = (t & 1) * 32;
    const int br = t >> 2, bc = (t & 3) * 16;

    const float* agf  = x  + (size_t)(m0 + ar) * 512 + ac;
    const float* bgf0 = Wq + (size_t)(h * 64 + br) * 512 + bc;
    const float* bgf1 = Wk + (size_t)(h * 64 + br) * 512 + bc;
    const float* bgf2 = Wv + (size_t)(h * 64 + br) * 512 + bc;

    const f32x4 kZero = {0.f, 0.f, 0.f, 0.f};
    f32x4 acc[3][2][4];
    #pragma unroll
    for (int c = 0; c < 3; ++c)
        #pragma unroll
        for (int i = 0; i < 2; ++i)
            #pragma unroll
            for (int j = 0; j < 4; ++j) acc[c][i][j] = kZero;

    for (int k0 = 0; k0 < 512; k0 += 64) {
        // load fp32, convert RTN immediately (same rounding as a cvt kernel)
        half8 av[4], bv[6];
        #pragma unroll
        for (int i = 0; i < 4; ++i) {
            float4 f0 = *(const float4*)(agf + k0 + i * 8);
            float4 f1 = *(const float4*)(agf + k0 + i * 8 + 4);
            half8 hv;
            hv[0] = (_Float16)f0.x; hv[1] = (_Float16)f0.y;
            hv[2] = (_Float16)f0.z; hv[3] = (_Float16)f0.w;
            hv[4] = (_Float16)f1.x; hv[5] = (_Float16)f1.y;
            hv[6] = (_Float16)f1.z; hv[7] = (_Float16)f1.w;
            av[i] = hv;
        }
        #pragma unroll
        for (int c = 0; c < 3; ++c) {
            const float* bp = (c == 0) ? bgf0 : (c == 1) ? bgf1 : bgf2;
            #pragma unroll
            for (int i = 0; i < 2; ++i) {
                float4 f0 = *(const float4*)(bp + k0 + i * 8);
                float4 f1 = *(const float4*)(bp + k0 + i * 8 + 4);
                half8 hv;
                hv[0] = (_Float16)f0.x; hv[1] = (_Float16)f0.y;
                hv[2] = (_Float16)f0.z; hv[3] = (_Float16)f0.w;
                hv[4] = (_Float16)f1.x; hv[5] = (_Float16)f1.y;
                hv[6] = (_Float16)f1.z; hv[7] = (_Float16)f1.w;
                bv[c * 2 + i] = hv;
            }
        }
        __syncthreads();
        #pragma unroll
        for (int i = 0; i < 4; ++i) *(half8*)&As[ar][ac + i * 8] = av[i];
        #pragma unroll
        for (int c = 0; c < 3; ++c) {
            *(half8*)&Bs[c * 64 + br][bc]     = bv[2 * c];
            *(half8*)&Bs[c * 64 + br][bc + 8] = bv[2 * c + 1];
        }
        __syncthreads();

        #pragma unroll
        for (int ks = 0; ks < 2; ++ks) {
            half8 af[2];
            #pragma unroll
            for (int mt = 0; mt < 2; ++mt)
                af[mt] = *(const half8*)&As[w * 32 + mt * 16 + ln][ks * 32 + quad * 8];
            #pragma unroll
            for (int c = 0; c < 3; ++c) {
                half8 bf[4];
                #pragma unroll
                for (int nt = 0; nt < 4; ++nt)
                    bf[nt] = *(const half8*)&Bs[c * 64 + nt * 16 + ln][ks * 32 + quad * 8];
                #pragma unroll
                for (int mt = 0; mt < 2; ++mt)
                    #pragma unroll
                    for (int nt = 0; nt < 4; ++nt)
                        acc[c][mt][nt] = MFMA32(af[mt], bf[nt], acc[c][mt][nt]);
            }
        }
    }

    const int b  = m0 >> 11;
    const int l0 = m0 & 2047;
    const float twopif = 6.28318530717958647692f * wf[h];
    const float ph     = wp[h];

    #pragma unroll
    for (int which = 0; which < 2; ++which) {
        _Float16* dst = (which == 0 ? Qh : Kh) + (size_t)(b * NHEAD + h) * SEQ * DK;
        __syncthreads();
        _Float16* Ql = &As[0][0];
        #pragma unroll
        for (int mt = 0; mt < 2; ++mt)
            #pragma unroll
            for (int r = 0; r < 4; ++r) {
                const int lr = w * 32 + mt * 16 + quad * 4 + r;
                float wv = 1.0f;
                if (which == 1)
                    wv = WSCALE * cosf(fmaf(twopif, (float)(l0 + lr), ph));
                #pragma unroll
                for (int nt = 0; nt < 4; ++nt)
                    Ql[lr * 72 + nt * 16 + ln] = (_Float16)(acc[which][mt][nt][r] * wv);
            }
        __syncthreads();
        #pragma unroll
        for (int rr = 0; rr < 4; ++rr) {
            const int row = rr * 32 + (t >> 3);
            half8 v = *(const half8*)&Ql[row * 72 + (t & 7) * 8];
            *(half8*)(dst + (size_t)(l0 + row) * DK + (t & 7) * 8) = v;
        }
    }

    __syncthreads();
    _Float16* Vl = &As[0][0];
    #pragma unroll
    for (int nt = 0; nt < 4; ++nt) {
        half8 hv;
        #pragma unroll
        for (int mt = 0; mt < 2; ++mt)
            #pragma unroll
            for (int r = 0; r < 4; ++r)
                hv[mt * 4 + r] = (_Float16)acc[2][mt][nt][r];
        const int d = nt * 16 + ln;
        *(half8*)&Vl[d * 136 + w * 32 + quad * 8] = hv;
    }
    __syncthreads();
    _Float16* dst = Vth + (size_t)(b * NHEAD + h) * DK * SEQ;
    #pragma unroll
    for (int rr = 0; rr < 4; ++rr) {
        const int d = rr * 16 + (t >> 4);
        half8 v = *(const half8*)&Vl[d * 136 + (t & 15) * 8];
        *(half8*)(dst + (size_t)d * SEQ + l0 + (t & 15) * 8) = v;
    }
}

// ---------------------------------------------------------------------------
// Kernel 2: flash attention — EXACT round-9 kernel (best measured: 45.9 us).
// grid: 512 linear, block 512
// ---------------------------------------------------------------------------
__global__ __launch_bounds__(512, 4) void attn_mfma_kernel(
    const _Float16* __restrict__ Qh, const _Float16* __restrict__ Kwh,
    const _Float16* __restrict__ Vth, _Float16* __restrict__ AOh)
{
    __shared__ _Float16 SM[2][4][64][72];   // 73.7 KB

    const int bx = blockIdx.x;           // 0..511
    const int g8 = bx & 7;               // XCD (dispatch round-robin)
    const int s  = bx >> 3;              // 0..63
    const int bh = g8 * 4 + (s >> 4);    // XCD g owns bh 4g..4g+3
    const int q0 = (s & 15) * 128;
    const int b = bh >> 3, h = bh & 7;

    const int t = threadIdx.x;           // 0..511
    const int w = t >> 6;                // 0..7
    const int wg = w & 3;                // q-row group
    const int half = w >> 2;             // key half
    const int lane = t & 63, ln = lane & 15, quad = lane >> 4;

    const _Float16* Qg = Qh + ((size_t)bh * SEQ + q0) * DK;
    const _Float16* Kg = Kwh + (size_t)bh * SEQ * DK;
    const _Float16* Vg = Vth + (size_t)bh * DK * SEQ;
    const int kbase = half * 1024;

    const int tl = t & 255;
    const int sr = tl >> 2, sc = (tl & 3) * 16;
    const int qr = t >> 2, qc = (t & 3) * 16;

    {
        const _Float16* qp = Qg + (size_t)qr * DK + qc;
        half8 qv0 = *(const half8*)(qp);
        half8 qv1 = *(const half8*)(qp + 8);
        const _Float16* kp = Kg + (size_t)(kbase + sr) * DK + sc;
        const _Float16* vp = Vg + (size_t)sr * SEQ + kbase + sc;
        half8 kv0 = *(const half8*)(kp);
        half8 kv1 = *(const half8*)(kp + 8);
        half8 vv0 = *(const half8*)(vp);
        half8 vv1 = *(const half8*)(vp + 8);
        _Float16* qd = &SM[1][2 + (qr >> 6)][qr & 63][qc];
        *(half8*)(qd)     = qv0;
        *(half8*)(qd + 8) = qv1;
        *(half8*)&SM[half][0][sr][sc]     = kv0;
        *(half8*)&SM[half][0][sr][sc + 8] = kv1;
        *(half8*)&SM[half][1][sr][sc]     = vv0;
        *(half8*)&SM[half][1][sr][sc + 8] = vv1;
    }
    __syncthreads();

    half8 qf[2][2];
    #pragma unroll
    for (int u = 0; u < 2; ++u) {
        const int row = wg * 32 + u * 16 + ln;
        const _Float16* qsrc = &SM[1][2 + (row >> 6)][row & 63][0];
        qf[u][0] = *(const half8*)(qsrc + quad * 8);
        qf[u][1] = *(const half8*)(qsrc + 32 + quad * 8);
    }
    // first write to SM[1][2..3] happens only after kt=0's in-loop barrier

    const f32x4 kZero = {0.f, 0.f, 0.f, 0.f};
    f32x4 o[2][4];
    #pragma unroll
    for (int u = 0; u < 2; ++u)
        #pragma unroll
        for (int nt = 0; nt < 4; ++nt) o[u][nt] = kZero;
    float l_acc[2] = {0.f, 0.f};

    for (int kt = 0; kt < 16; ++kt) {
        const int cur = kt & 1;

        half8 pk0, pk1, pv0, pv1;
        const bool more = (kt + 1 < 16);
        if (more) {
            const _Float16* kp = Kg + (size_t)(kbase + (kt + 1) * 64 + sr) * DK + sc;
            const _Float16* vp = Vg + (size_t)sr * SEQ + kbase + (kt + 1) * 64 + sc;
            pk0 = *(const half8*)(kp);
            pk1 = *(const half8*)(kp + 8);
            pv0 = *(const half8*)(vp);
            pv1 = *(const half8*)(vp + 8);
        }

        const _Float16 (*Ks)[72] = SM[half][2 * cur];
        const _Float16 (*Vs)[72] = SM[half][2 * cur + 1];

        #pragma unroll
        for (int g = 0; g < 2; ++g) {
            half8 ka0 = *(const half8*)&Ks[(2 * g + 0) * 16 + ln][quad * 8];
            half8 ka1 = *(const half8*)&Ks[(2 * g + 0) * 16 + ln][32 + quad * 8];
            half8 kb0 = *(const half8*)&Ks[(2 * g + 1) * 16 + ln][quad * 8];
            half8 kb1 = *(const half8*)&Ks[(2 * g + 1) * 16 + ln][32 + quad * 8];
            half8 vf[4];
            #pragma unroll
            for (int nt = 0; nt < 4; ++nt)
                vf[nt] = *(const half8*)&Vs[nt * 16 + ln][g * 32 + quad * 8];

            #pragma unroll
            for (int u = 0; u < 2; ++u) {
                f32x4 s0 = MFMA32(ka0, qf[u][0], kZero);
                f32x4 s1 = MFMA32(kb0, qf[u][0], kZero);
                s0 = MFMA32(ka1, qf[u][1], s0);
                s1 = MFMA32(kb1, qf[u][1], s1);

                const float e00 = __builtin_amdgcn_exp2f(s0[0]);
                const float e01 = __builtin_amdgcn_exp2f(s0[1]);
                const float e02 = __builtin_amdgcn_exp2f(s0[2]);
                const float e03 = __builtin_amdgcn_exp2f(s0[3]);
                const float e10 = __builtin_amdgcn_exp2f(s1[0]);
                const float e11 = __builtin_amdgcn_exp2f(s1[1]);
                const float e12 = __builtin_amdgcn_exp2f(s1[2]);
                const float e13 = __builtin_amdgcn_exp2f(s1[3]);
                union { half8 v; fp16x2 h2[4]; } pu;
                pu.h2[0] = __builtin_amdgcn_cvt_pkrtz(e00, e01);
                pu.h2[1] = __builtin_amdgcn_cvt_pkrtz(e02, e03);
                pu.h2[2] = __builtin_amdgcn_cvt_pkrtz(e10, e11);
                pu.h2[3] = __builtin_amdgcn_cvt_pkrtz(e12, e13);
                l_acc[u] += ((e00 + e01) + (e02 + e03)) + ((e10 + e11) + (e12 + e13));

                #pragma unroll
                for (int nt = 0; nt < 4; ++nt)
                    o[u][nt] = MFMA32(pu.v, vf[nt], o[u][nt]);
            }
        }

        __syncthreads();
        if (more) {
            _Float16* kd = &SM[half][2 * (cur ^ 1)][sr][sc];
            _Float16* vd = &SM[half][2 * (cur ^ 1) + 1][sr][sc];
            *(half8*)(kd)     = pk0;
            *(half8*)(kd + 8) = pk1;
            *(half8*)(vd)     = pv0;
            *(half8*)(vd + 8) = pv1;
        }
        __syncthreads();
    }

    float* OP = (float*)&SM[0][0][0][0];      // 34 slots x 257 floats
    const int idx = wg * 64 + lane;
    if (half == 1) {
        #pragma unroll
        for (int u = 0; u < 2; ++u)
            #pragma unroll
            for (int nt = 0; nt < 4; ++nt)
                #pragma unroll
                for (int r = 0; r < 4; ++r)
                    OP[((u * 4 + nt) * 4 + r) * 257 + idx] = o[u][nt][r];
        OP[32 * 257 + idx] = l_acc[0];
        OP[33 * 257 + idx] = l_acc[1];
    }
    __syncthreads();
    if (half == 0) {
        #pragma unroll
        for (int u = 0; u < 2; ++u)
            #pragma unroll
            for (int nt = 0; nt < 4; ++nt)
                #pragma unroll
                for (int r = 0; r < 4; ++r)
                    o[u][nt][r] += OP[((u * 4 + nt) * 4 + r) * 257 + idx];
        l_acc[0] += OP[32 * 257 + idx];
        l_acc[1] += OP[33 * 257 + idx];

        #pragma unroll
        for (int u = 0; u < 2; ++u) {
            l_acc[u] += __shfl_xor(l_acc[u], 16);
            l_acc[u] += __shfl_xor(l_acc[u], 32);
        }

        #pragma unroll
        for (int u = 0; u < 2; ++u)
            #pragma unroll
            for (int r = 0; r < 4; ++r) {
                const float lr  = __shfl(l_acc[u], quad * 4 + r, 16);
                const float inv = 1.0f / lr;
                const int lq = q0 + wg * 32 + u * 16 + quad * 4 + r;
                const size_t base = ((size_t)b * SEQ + lq) * D_MODEL + h * DK;
                #pragma unroll
                for (int nt = 0; nt < 4; ++nt)
                    AOh[base + nt * 16 + ln] = (_Float16)(o[u][nt][r] * inv);
            }
    }
}

// ---------------------------------------------------------------------------
// Kernel 3: output projection, fp16 MFMA.  out = AOh @ Wo^T (fp32 out),
//   Wo converted inline (RTN).  GRID ORDER FIX: blockIdx.x = m-tile (fast)
//   -> all 8 n-blocks for one A tile share one XCD's L2.
// grid: (64, 8), block 256
// ---------------------------------------------------------------------------
__global__ __launch_bounds__(256) void out_mfma_kernel(
    const _Float16* __restrict__ AOh, const float* __restrict__ Wo,
    float* __restrict__ out)
{
    __shared__ _Float16 As[128][72];
    __shared__ _Float16 Bs[64][72];

    const int t  = threadIdx.x;
    const int m0 = blockIdx.x * 128;   // FAST dim -> XCD = blockIdx.x % 8
    const int n0 = blockIdx.y * 64;

    const int w = t >> 6, lane = t & 63, ln = lane & 15, quad = lane >> 4;
    const int ar = t >> 1, ac = (t & 1) * 32;
    const int br = t >> 2, bc = (t & 3) * 16;

    const _Float16* ag  = AOh + (size_t)(m0 + ar) * 512 + ac;
    const float*    bgf = Wo  + (size_t)(n0 + br) * 512 + bc;

    const f32x4 kZero = {0.f, 0.f, 0.f, 0.f};
    f32x4 acc[2][4];
    #pragma unroll
    for (int i = 0; i < 2; ++i)
        #pragma unroll
        for (int j = 0; j < 4; ++j) acc[i][j] = kZero;

    for (int k0 = 0; k0 < 512; k0 += 64) {
        half8 av[4], bv[2];
        #pragma unroll
        for (int i = 0; i < 4; ++i) av[i] = *(const half8*)(ag + k0 + i * 8);
        #pragma unroll
        for (int i = 0; i < 2; ++i) {
            float4 f0 = *(const float4*)(bgf + k0 + i * 8);
            float4 f1 = *(const float4*)(bgf + k0 + i * 8 + 4);
            half8 hv;
            hv[0] = (_Float16)f0.x; hv[1] = (_Float16)f0.y;
            hv[2] = (_Float16)f0.z; hv[3] = (_Float16)f0.w;
            hv[4] = (_Float16)f1.x; hv[5] = (_Float16)f1.y;
            hv[6] = (_Float16)f1.z; hv[7] = (_Float16)f1.w;
            bv[i] = hv;
        }
        __syncthreads();
        #pragma unroll
        for (int i = 0; i < 4; ++i) *(half8*)&As[ar][ac + i * 8] = av[i];
        #pragma unroll
        for (int i = 0; i < 2; ++i) *(half8*)&Bs[br][bc + i * 8] = bv[i];
        __syncthreads();

        #pragma unroll
        for (int ks = 0; ks < 2; ++ks) {
            half8 af[2], bf[4];
            #pragma unroll
            for (int mt = 0; mt < 2; ++mt)
                af[mt] = *(const half8*)&As[w * 32 + mt * 16 + ln][ks * 32 + quad * 8];
            #pragma unroll
            for (int nt = 0; nt < 4; ++nt)
                bf[nt] = *(const half8*)&Bs[nt * 16 + ln][ks * 32 + quad * 8];
            #pragma unroll
            for (int mt = 0; mt < 2; ++mt)
                #pragma unroll
                for (int nt = 0; nt < 4; ++nt)
                    acc[mt][nt] = MFMA32(af[mt], bf[nt], acc[mt][nt]);
        }
    }

    float* Os = (float*)&As[0][0];     // [64][66] floats
    #pragma unroll
    for (int pass = 0; pass < 2; ++pass) {
        __syncthreads();
        if ((w >> 1) == pass) {
            const int rbase = (w & 1) * 32;
            #pragma unroll
            for (int mt = 0; mt < 2; ++mt)
                #pragma unroll
                for (int r = 0; r < 4; ++r) {
                    const int row = rbase + mt * 16 + quad * 4 + r;
                    #pragma unroll
                    for (int nt = 0; nt < 4; ++nt)
                        Os[row * 66 + nt * 16 + ln] = acc[mt][nt][r];
                }
        }
        __syncthreads();
        #pragma unroll
        for (int rr = 0; rr < 4; ++rr) {
            const int row = rr * 16 + (t >> 4);
            float4 v = *(const float4*)&Os[row * 66 + (t & 15) * 4];
            *(float4*)(out + (size_t)(m0 + pass * 64 + row) * 512 + n0 + (t & 15) * 4) = v;
        }
    }
}

// ---------------------------------------------------------------------------
extern "C" void kernel_launch(void* const* d_in, const int* in_sizes, int n_in,
                              void* d_out, int out_size, void* d_ws, size_t ws_size,
                              hipStream_t stream)
{
    (void)in_sizes; (void)n_in; (void)out_size; (void)ws_size;
    const float* x  = (const float*)d_in[0];
    const float* Wq = (const float*)d_in[1];
    const float* Wk = (const float*)d_in[2];
    const float* Wv = (const float*)d_in[3];
    const float* Wo = (const float*)d_in[4];
    const float* wf = (const float*)d_in[5];
    const float* wp = (const float*)d_in[6];
    float* out = (float*)d_out;

    const size_t NX = (size_t)MTOT * D_MODEL;        // 4,194,304
    _Float16* Qh  = (_Float16*)d_ws;
    _Float16* Kh  = Qh + NX;                          // pre-scaled K'
    _Float16* Vth = Kh + NX;                          // transposed+swizzled V
    _Float16* AOh = Vth + NX;

    dim3 g1(64, 8);
    qkv_mfma_kernel<<<g1, 256, 0, stream>>>(x, Wq, Wk, Wv, wf, wp, Qh, Kh, Vth);

    attn_mfma_kernel<<<512, 512, 0, stream>>>(Qh, Kh, Vth, AOh);

    dim3 g3(64, 8);
    out_mfma_kernel<<<g3, 256, 0, stream>>>(AOh, Wo, out);
}